// Round 2
// baseline (26.712 us; speedup 1.0000x reference)
//
#include <hip/hip_runtime.h>
#include <hip/hip_bf16.h>

#define EPSV 1e-6f

// Two threads per (n,i) row: lane-pair (2m, 2m+1) shares row m; half h=g&1
// handles j = 4h..4h+3. 16-lane groups = one sample n. All 8 survival gathers
// are issued before any transcendental work. Transpose + diagonals via two
// padded LDS tiles.
__global__ __launch_bounds__(256) void rank_partial2(
    const float* __restrict__ durations,
    const float* __restrict__ survival,
    const float* __restrict__ hazard,
    const float* __restrict__ cuts,
    const int* __restrict__ events,
    float* __restrict__ partials,
    int NE, int K)
{
    __shared__ float s_cuts[256];     // K == 256 here
    __shared__ float s_S [128][9];    // SatT tile (+1 pad)
    __shared__ float s_SM[128][9];    // SatTMinus tile (+1 pad)
    __shared__ float s_wsum[4];

    const int tid = threadIdx.x;
    for (int k = tid; k < K; k += 256) s_cuts[k] = cuts[k];
    __syncthreads();

    const int g  = blockIdx.x * 256 + tid;
    const int r  = g >> 1;          // global row = n*8 + i
    const int h  = g & 1;           // j-half: 0 -> j=0..3, 1 -> j=4..7
    const int ri = tid >> 1;        // row within block tile (0..127)
    const int i  = ri & 7;          // i within sample
    const bool valid = r < NE;

    const float d_i  = valid ? durations[r] : 0.f;
    const int   ev_i = valid ? events[r]    : 0;

    // t0 = largest k with cuts[k] <= d  (analytic guess + exact fixup)
    const float c0 = s_cuts[0], cK = s_cuts[K - 1];
    int t0 = (int)((d_i - c0) * (float)(K - 1) / (cK - c0));
    t0 = max(0, min(t0, K - 1));
    while (t0 + 1 < K && s_cuts[t0 + 1] <= d_i) ++t0;
    while (t0 > 0 && s_cuts[t0] > d_i) --t0;
    const int t1 = (t0 + 1 < K) ? t0 + 1 : K - 1;
    const float T0_i = s_cuts[t0];
    const float dT_i = s_cuts[t1] - T0_i;
    const float t_eps = (cK - c0) / cK;

    const float* __restrict__ srow = survival + (long long)r * K;

    // Phase 1: shuffle row-j metadata, issue all 8 gathers
    float d_j4[4], T0j[4], dTj[4];
    int t0j[4], evj[4];
    #pragma unroll
    for (int q = 0; q < 4; ++q) {
        const int j = 4 * h + q;
        const int src = 2 * j;            // lane within 16-group holding row j
        d_j4[q] = __shfl(d_i,  src, 16);
        t0j[q]  = __shfl(t0,   src, 16);
        T0j[q]  = __shfl(T0_i, src, 16);
        dTj[q]  = __shfl(dT_i, src, 16);
        evj[q]  = __shfl(ev_i, src, 16);
    }
    float S0[4], S1[4];
    #pragma unroll
    for (int q = 0; q < 4; ++q) {
        const int a = t0j[q];
        const int b = (a + 1 < K) ? a + 1 : K - 1;
        S0[q] = valid ? srow[a] : 1.f;
        S1[q] = valid ? srow[b] : 1.f;
    }

    // Phase 2: hstar, SatT, SatTMinus
    float sT[4], sTM[4];
    #pragma unroll
    for (int q = 0; q < 4; ++q) {
        float hstar;
        if (dTj[q] > 0.f)
            hstar = (__logf(EPSV + S0[q]) - __logf(EPSV + S1[q])) / dTj[q];
        else
            hstar = valid ? hazard[(long long)r * K + t0j[q]] : 0.f; // dead here
        sT[q]  = S0[q] * __expf(-(d_j4[q] - T0j[q]) * hstar);
        const float tm = fmaxf(d_j4[q] - t_eps, 0.f);
        sTM[q] = S0[q] * __expf(-(tm - T0j[q]) * hstar);
        s_S [ri][4 * h + q] = sT[q];
        s_SM[ri][4 * h + q] = sTM[q];
    }
    __syncthreads();

    // Phase 3: pair terms
    const float I_i = (float)ev_i;
    const float diagS_i = s_S[ri][i];     // SatT[i][i]
    const int rbase = ri & ~7;            // sample's first row in tile
    float acc = 0.f;
    #pragma unroll
    for (int q = 0; q < 4; ++q) {
        const int j = 4 * h + q;
        // A1 = I_i * (d_j > d_i); skip exps when zero (~75% of pairs)
        if (I_i != 0.f && d_j4[q] > d_i) {
            const int rj = rbase + j;
            const float I_j = (float)evj[q];
            const float e1 = __expf(diagS_i - s_S[rj][i]);   // dS1[i][j]
            const float e2 = __expf(sTM[q] - s_SM[rj][j]);   // dS2[i][j]
            const float e3 = __expf(sT[q]  - s_S [rj][j]);   // dS3[i][j]
            acc += e1 + I_j * e2 + (1.f - I_j) * e3;
        }
    }

    // deterministic wave reduce -> block partial
    #pragma unroll
    for (int off = 32; off > 0; off >>= 1) acc += __shfl_down(acc, off, 64);
    if ((tid & 63) == 0) s_wsum[tid >> 6] = acc;
    __syncthreads();
    if (tid == 0)
        partials[blockIdx.x] = (s_wsum[0] + s_wsum[1]) + (s_wsum[2] + s_wsum[3]);
}

__global__ __launch_bounds__(256) void rank_finalize(
    const float* __restrict__ partials, int nb,
    const float* __restrict__ weights,
    float* __restrict__ out, float inv_count)
{
    __shared__ float s[256];
    const int tid = threadIdx.x;
    float a = 0.f;
    for (int idx = tid; idx < nb; idx += 256) a += partials[idx];
    s[tid] = a;
    __syncthreads();
    #pragma unroll
    for (int off = 128; off > 0; off >>= 1) {
        if (tid < off) s[tid] += s[tid + off];
        __syncthreads();
    }
    if (tid == 0) out[0] = s[0] * weights[0] * inv_count;
}

extern "C" void kernel_launch(void* const* d_in, const int* in_sizes, int n_in,
                              void* d_out, int out_size, void* d_ws, size_t ws_size,
                              hipStream_t stream) {
    const float* durations = (const float*)d_in[0];
    const float* survival  = (const float*)d_in[1];
    const float* hazard    = (const float*)d_in[2];
    const float* weights   = (const float*)d_in[3];
    const float* cuts      = (const float*)d_in[4];
    const int*   events    = (const int*)d_in[5];

    const int NE = in_sizes[0];              // N * 8 rows
    const int K  = in_sizes[4];              // 256
    const int nthreads = NE * 2;             // 2 threads per row
    const int nb = (nthreads + 255) / 256;   // 1024 blocks

    float* partials = (float*)d_ws;
    float* out = (float*)d_out;

    rank_partial2<<<nb, 256, 0, stream>>>(durations, survival, hazard, cuts,
                                          events, partials, NE, K);

    const float inv_count = 1.0f / ((float)NE * 8.0f);   // mean over n*e*e
    rank_finalize<<<1, 256, 0, stream>>>(partials, nb, weights, out, inv_count);
}